// Round 15
// baseline (113.536 us; speedup 1.0000x reference)
//
#include <hip/hip_runtime.h>

#define IMG_H 1024
#define IMG_W 1024

#define CC  (-0.1803368801111244f)     // -(1/8)*log2(e)
#define WS1 (-2.8853900817779270e-4f)  // log2(exp(-1/5000))
#define WS2 (-5.7707801635558540e-4f)  // log2(exp(-2/5000))

typedef __attribute__((ext_vector_type(2))) float f32x2;

__device__ __forceinline__ f32x2 earg2(f32x2 u, f32x2 v, float ws) {
    f32x2 d = u - v;
    return __builtin_elementwise_fma(d * d, (f32x2)CC, (f32x2)ws);
}
__device__ __forceinline__ float earg1(float u, float v, float ws) {
    float d = u - v;
    return fmaf(d * d, CC, ws);
}

// packed exp2 on the full-rate VALU pipe (no trans unit).
// t = y + 1.5*2^23 (RN) -> n=round(y) in low mantissa; f = y-n in [-0.5,0.5];
// degree-4 poly for 2^f; exponent inserted via (bits(t)<<23)+bits(p)
// (exact: low 9 bits of 0x4B400000 are zero). abs err ~5e-5, y in (-120,0].
__device__ __forceinline__ f32x2 exp2p(f32x2 y) {
    f32x2 t = y + (f32x2)12582912.0f;
    f32x2 f = y - (t - (f32x2)12582912.0f);
    f32x2 p = __builtin_elementwise_fma(f, (f32x2)0.0096181291f, (f32x2)0.0555041087f);
    p = __builtin_elementwise_fma(f, p, (f32x2)0.2402265070f);
    p = __builtin_elementwise_fma(f, p, (f32x2)0.6931471806f);
    p = __builtin_elementwise_fma(f, p, (f32x2)1.0f);
    f32x2 r;
    r.x = __int_as_float((__float_as_int(t.x) << 23) + __float_as_int(p.x));
    r.y = __int_as_float((__float_as_int(t.y) << 23) + __float_as_int(p.y));
    return r;
}

__global__ __launch_bounds__(256, 4) void EdgePreserve_kernel(const float* __restrict__ x,
                                                              float* __restrict__ out) {
    const int t   = threadIdx.x;
    const int bid = blockIdx.x;         // b*64 + pool_row
    const int b   = bid >> 6;
    const int pr  = bid & 63;
    const int r0  = pr << 4;
    const int c0  = t << 2;             // 4 cols per thread

    const float* base = x + (size_t)b * (IMG_H * IMG_W);
    const int cl = (c0 == 0) ? 1 : c0 - 1;
    const int cr = (c0 + 4 >= IMG_W) ? IMG_W - 2 : c0 + 4;

    // 6 row buffers: A=r-1, B=r, C=r+1, D=r+2; E,F = prefetch r+3, r+4
    float a0,a1,a2,a3,a4,a5, b0,b1,b2,b3,b4,b5, c1_0,c1_1,c1_2,c1_3,c1_4,c1_5,
          d0,d1,d2,d3,d4,d5, e0,e1,e2_,e3,e4,e5, f0,f1,f2,f3,f4,f5;

#define LOADROW(q, w0,w1,w2,w3,w4,w5) { \
    int _r = r0 + (q); \
    int _rr = (_r < 0) ? -_r : ((_r >= IMG_H) ? (2*IMG_H-2-_r) : _r); \
    const float* _rp = base + _rr * IMG_W; \
    float4 _v = *reinterpret_cast<const float4*>(_rp + c0); \
    w0 = _rp[cl]; w1 = _v.x; w2 = _v.y; w3 = _v.z; w4 = _v.w; w5 = _rp[cr]; }

    LOADROW(-1, a0,a1,a2,a3,a4,a5)
    LOADROW( 0, b0,b1,b2,b3,b4,b5)
    LOADROW( 1, c1_0,c1_1,c1_2,c1_3,c1_4,c1_5)
    LOADROW( 2, d0,d1,d2,d3,d4,d5)

    // carried A-B edges (12 weights in 6 pairs):
    // cV12={V1,V2} cV34={V3,V4} cDR01={DR0,DR1} cDR23={DR2,DR3} cDL23={DL2,DL3} cDL45={DL4,DL5}
    f32x2 cV12  = exp2p(earg2((f32x2){a1,a2}, (f32x2){b1,b2}, WS1));
    f32x2 cV34  = exp2p(earg2((f32x2){a3,a4}, (f32x2){b3,b4}, WS1));
    f32x2 cDR01 = exp2p(earg2((f32x2){a0,a1}, (f32x2){b1,b2}, WS2));
    f32x2 cDR23 = exp2p(earg2((f32x2){a2,a3}, (f32x2){b3,b4}, WS2));
    f32x2 cDL23 = exp2p(earg2((f32x2){a2,a3}, (f32x2){b1,b2}, WS2));
    f32x2 cDL45 = exp2p(earg2((f32x2){a4,a5}, (f32x2){b3,b4}, WS2));

    f32x2 psum = (f32x2){0.0f, 0.0f};

#define PIXPAIR(ctr, nAL,nAC,nAR, nBL,nBR, nKL,nKC,nKR, wAL,wAC,wAR, wBL,wBR, wKL,wKC,wKR) { \
        f32x2 num = ctr; \
        num = __builtin_elementwise_fma(wAL, nAL, num); \
        num = __builtin_elementwise_fma(wAC, nAC, num); \
        num = __builtin_elementwise_fma(wAR, nAR, num); \
        num = __builtin_elementwise_fma(wBL, nBL, num); \
        num = __builtin_elementwise_fma(wBR, nBR, num); \
        num = __builtin_elementwise_fma(wKL, nKL, num); \
        num = __builtin_elementwise_fma(wKC, nKC, num); \
        num = __builtin_elementwise_fma(wKR, nKR, num); \
        f32x2 den = ((wAL + wAC) + (wAR + wBL)) + ((wBR + wKL) + (wKC + wKR)); \
        den = den + (f32x2)1.0f; \
        f32x2 rc = (f32x2){__builtin_amdgcn_rcpf(den.x), __builtin_amdgcn_rcpf(den.y)}; \
        psum = __builtin_elementwise_fma(num, rc, psum); }

    // 8 fused iterations, 2 image rows each; fully unrolled
    #pragma unroll
    for (int i = 0; i < 8; ++i) {
        LOADROW(2*i + 3, e0,e1,e2_,e3,e4,e5)
        LOADROW(2*i + 4, f0,f1,f2,f3,f4,f5)

        // ---- 19 packed edge args ----
        f32x2 A_HB01 = earg2((f32x2){b0,b1}, (f32x2){b1,b2}, WS1);
        f32x2 A_HB23 = earg2((f32x2){b2,b3}, (f32x2){b3,b4}, WS1);
        f32x2 A_HC01 = earg2((f32x2){c1_0,c1_1}, (f32x2){c1_1,c1_2}, WS1);
        f32x2 A_HC23 = earg2((f32x2){c1_2,c1_3}, (f32x2){c1_3,c1_4}, WS1);
        f32x2 A_BV12 = earg2((f32x2){b1,b2}, (f32x2){c1_1,c1_2}, WS1);
        f32x2 A_BV34 = earg2((f32x2){b3,b4}, (f32x2){c1_3,c1_4}, WS1);
        f32x2 A_BDL12= earg2((f32x2){b1,b2}, (f32x2){c1_0,c1_1}, WS2);
        f32x2 A_BDL34= earg2((f32x2){b3,b4}, (f32x2){c1_2,c1_3}, WS2);
        f32x2 A_BDR01= earg2((f32x2){b0,b1}, (f32x2){c1_1,c1_2}, WS2);
        f32x2 A_BDR23= earg2((f32x2){b2,b3}, (f32x2){c1_3,c1_4}, WS2);
        f32x2 A_CV12 = earg2((f32x2){c1_1,c1_2}, (f32x2){d1,d2}, WS1);
        f32x2 A_CV34 = earg2((f32x2){c1_3,c1_4}, (f32x2){d3,d4}, WS1);
        f32x2 A_CDL12= earg2((f32x2){c1_1,c1_2}, (f32x2){d0,d1}, WS2);
        f32x2 A_CDL34= earg2((f32x2){c1_3,c1_4}, (f32x2){d2,d3}, WS2);
        f32x2 A_CDR01= earg2((f32x2){c1_0,c1_1}, (f32x2){d1,d2}, WS2);
        f32x2 A_CDR23= earg2((f32x2){c1_2,c1_3}, (f32x2){d3,d4}, WS2);
        f32x2 A_T1 = (f32x2){earg1(b4,b5,WS1),     earg1(c1_4,c1_5,WS1)};  // HB4, HC4
        f32x2 A_T2 = (f32x2){earg1(b5,c1_4,WS2),   earg1(b4,c1_5,WS2)};    // BDL5, BDR4
        f32x2 A_T3 = (f32x2){earg1(c1_5,d4,WS2),   earg1(c1_4,d5,WS2)};    // CDL5, CDR4

        // ---- 19 packed poly exp2 (VALU pipe, no trans) ----
        f32x2 HB01 = exp2p(A_HB01), HB23 = exp2p(A_HB23);
        f32x2 HC01 = exp2p(A_HC01), HC23 = exp2p(A_HC23);
        f32x2 BV12 = exp2p(A_BV12), BV34 = exp2p(A_BV34);
        f32x2 BDL12= exp2p(A_BDL12), BDL34= exp2p(A_BDL34);
        f32x2 BDR01= exp2p(A_BDR01), BDR23= exp2p(A_BDR23);
        f32x2 CV12 = exp2p(A_CV12), CV34 = exp2p(A_CV34);
        f32x2 CDL12= exp2p(A_CDL12), CDL34= exp2p(A_CDL34);
        f32x2 CDR01= exp2p(A_CDR01), CDR23= exp2p(A_CDR23);
        f32x2 T1 = exp2p(A_T1), T2 = exp2p(A_T2), T3 = exp2p(A_T3);
        float HB4 = T1.x, HC4 = T1.y, BDL5 = T2.x, BDR4 = T2.y, CDL5 = T3.x, CDR4 = T3.y;

        // pair views of rows
        f32x2 a01={a0,a1}, a12={a1,a2}, a23={a2,a3}, a34={a3,a4}, a45={a4,a5};
        f32x2 b01={b0,b1}, b12={b1,b2}, b23={b2,b3}, b34={b3,b4}, b45={b4,b5};
        f32x2 c01={c1_0,c1_1}, c12={c1_1,c1_2}, c23={c1_2,c1_3}, c34={c1_3,c1_4}, c45={c1_4,c1_5};
        f32x2 d01={d0,d1}, d12={d1,d2}, d23={d2,d3}, d34={d3,d4}, d45={d4,d5};

        // ---- image row 2i (center B): up = carried A-B, down = B-C ----
        PIXPAIR(b12, a01,a12,a23, b01,b23, c01,c12,c23,
                cDR01, cV12, cDL23,
                HB01, ((f32x2){HB01.y,HB23.x}),
                BDL12, BV12, ((f32x2){BDR01.y,BDR23.x}))
        PIXPAIR(b34, a23,a34,a45, b23,b45, c23,c34,c45,
                cDR23, cV34, cDL45,
                HB23, ((f32x2){HB23.y,HB4}),
                BDL34, BV34, ((f32x2){BDR23.y,BDR4}))

        // ---- image row 2i+1 (center C): up = B-C, down = C-D ----
        PIXPAIR(c12, b01,b12,b23, c01,c23, d01,d12,d23,
                BDR01, BV12, ((f32x2){BDL12.y,BDL34.x}),
                HC01, ((f32x2){HC01.y,HC23.x}),
                CDL12, CV12, ((f32x2){CDR01.y,CDR23.x}))
        PIXPAIR(c34, b23,b34,b45, c23,c45, d23,d34,d45,
                BDR23, BV34, ((f32x2){BDL34.y,BDL5}),
                HC23, ((f32x2){HC23.y,HC4}),
                CDL34, CV34, ((f32x2){CDR23.y,CDR4}))

        // rotate rows by 2 (full unroll -> renaming)
        a0=c1_0;a1=c1_1;a2=c1_2;a3=c1_3;a4=c1_4;a5=c1_5;
        b0=d0;b1=d1;b2=d2;b3=d3;b4=d4;b5=d5;
        c1_0=e0;c1_1=e1;c1_2=e2_;c1_3=e3;c1_4=e4;c1_5=e5;
        d0=f0;d1=f1;d2=f2;d3=f3;d4=f4;d5=f5;
        // carried = this iter's C-D edges
        cV12 = CV12; cV34 = CV34; cDR01 = CDR01; cDR23 = CDR23;
        cDL23 = (f32x2){CDL12.y, CDL34.x};
        cDL45 = (f32x2){CDL34.y, CDL5};
    }
#undef PIXPAIR
#undef LOADROW

    float ps = psum.x + psum.y;
    ps += __shfl_xor(ps, 1);
    ps += __shfl_xor(ps, 2);

    if ((t & 3) == 0) {
        out[(size_t)bid * 64 + (t >> 2)] = ps * (1.0f / 256.0f);
    }
}

extern "C" void kernel_launch(void* const* d_in, const int* in_sizes, int n_in,
                              void* d_out, int out_size, void* d_ws, size_t ws_size,
                              hipStream_t stream) {
    const float* x = (const float*)d_in[0];
    float* out     = (float*)d_out;
    // 1024 blocks x 256 threads (4 cols x 16 rows each), 4 blocks/CU resident
    EdgePreserve_kernel<<<dim3(16 * 64), dim3(256), 0, stream>>>(x, out);
}

// Round 16
// 49.594 us; speedup vs baseline: 2.2893x; 2.2893x over previous
//
#include <hip/hip_runtime.h>

#define IMG_H 1024
#define IMG_W 1024

#define CC  (-0.1803368801111244f)     // -(1/8)*log2(e)
#define WS1 (-2.8853900817779270e-4f)  // log2(exp(-1/5000))
#define WS2 (-5.7707801635558540e-4f)  // log2(exp(-2/5000))

typedef __attribute__((ext_vector_type(2))) float f32x2;

__device__ __forceinline__ f32x2 earg2(f32x2 u, f32x2 v, float ws) {
    f32x2 d = u - v;
    return __builtin_elementwise_fma(d * d, (f32x2)CC, (f32x2)ws);
}
__device__ __forceinline__ float earg1(float u, float v, float ws) {
    float d = u - v;
    return fmaf(d * d, CC, ws);
}

// packed exp2 on the full-rate VALU pipe (no trans unit).
// t = y + 1.5*2^23 (RN) -> n=round(y); f = y-n in [-0.5,0.5]; degree-4 poly;
// exponent inserted via (bits(t)<<23)+bits(p) (exact: low 9 bits of
// 0x4B400000 are zero). abs err ~5e-5, valid for y in (-120, 0].
__device__ __forceinline__ f32x2 exp2p(f32x2 y) {
    f32x2 t = y + (f32x2)12582912.0f;
    f32x2 f = y - (t - (f32x2)12582912.0f);
    f32x2 p = __builtin_elementwise_fma(f, (f32x2)0.0096181291f, (f32x2)0.0555041087f);
    p = __builtin_elementwise_fma(f, p, (f32x2)0.2402265070f);
    p = __builtin_elementwise_fma(f, p, (f32x2)0.6931471806f);
    p = __builtin_elementwise_fma(f, p, (f32x2)1.0f);
    f32x2 r;
    r.x = __int_as_float((__float_as_int(t.x) << 23) + __float_as_int(p.x));
    r.y = __int_as_float((__float_as_int(t.y) << 23) + __float_as_int(p.y));
    return r;
}

__global__ __launch_bounds__(256) void EdgePreserve_kernel(const float* __restrict__ x,
                                                           float* __restrict__ out) {
    const int t   = threadIdx.x;
    const int bid = blockIdx.x;         // b*64 + pool_row
    const int b   = bid >> 6;
    const int pr  = bid & 63;
    const int r0  = pr << 4;
    const int c0  = t << 2;             // 4 cols per thread

    const float* base = x + (size_t)b * (IMG_H * IMG_W);
    const int cl = (c0 == 0) ? 1 : c0 - 1;
    const int cr = (c0 + 4 >= IMG_W) ? IMG_W - 2 : c0 + 4;

    // 4 row buffers (R13 structure): a=r-1, b=r, k=r+1, p=prefetch
    float a0,a1,a2,a3,a4,a5, b0,b1,b2,b3,b4,b5, k0,k1,k2,k3,k4,k5, p0,p1,p2,p3,p4,p5;

#define LOADROW(q, d0,d1,d2,d3,d4,d5) { \
    int _r = r0 + (q); \
    int _rr = (_r < 0) ? -_r : ((_r >= IMG_H) ? (2*IMG_H-2-_r) : _r); \
    const float* _rp = base + _rr * IMG_W; \
    float4 _v = *reinterpret_cast<const float4*>(_rp + c0); \
    d0 = _rp[cl]; d1 = _v.x; d2 = _v.y; d3 = _v.z; d4 = _v.w; d5 = _rp[cr]; }

    LOADROW(-1, a0,a1,a2,a3,a4,a5)
    LOADROW( 0, b0,b1,b2,b3,b4,b5)
    LOADROW( 1, k0,k1,k2,k3,k4,k5)
    LOADROW( 2, p0,p1,p2,p3,p4,p5)

    // carried A-B edge weights (6 pairs):
    // cV12={V1,V2} cV34={V3,V4} cDR01={DR0,DR1} cDR23={DR2,DR3} cDL23={DL2,DL3} cDL45={DL4,DL5}
    f32x2 cV12  = exp2p(earg2((f32x2){a1,a2}, (f32x2){b1,b2}, WS1));
    f32x2 cV34  = exp2p(earg2((f32x2){a3,a4}, (f32x2){b3,b4}, WS1));
    f32x2 cDR01 = exp2p(earg2((f32x2){a0,a1}, (f32x2){b1,b2}, WS2));
    f32x2 cDR23 = exp2p(earg2((f32x2){a2,a3}, (f32x2){b3,b4}, WS2));
    f32x2 cDL23 = exp2p(earg2((f32x2){a2,a3}, (f32x2){b1,b2}, WS2));
    f32x2 cDL45 = exp2p(earg2((f32x2){a4,a5}, (f32x2){b3,b4}, WS2));

    f32x2 psum = (f32x2){0.0f, 0.0f};

#define PIXPAIR(ctr, nAL,nAC,nAR, nBL,nBR, nKL,nKC,nKR, wAL,wAC,wAR, wBL,wBR, wKL,wKC,wKR) { \
        f32x2 num = ctr; \
        num = __builtin_elementwise_fma(wAL, nAL, num); \
        num = __builtin_elementwise_fma(wAC, nAC, num); \
        num = __builtin_elementwise_fma(wAR, nAR, num); \
        num = __builtin_elementwise_fma(wBL, nBL, num); \
        num = __builtin_elementwise_fma(wBR, nBR, num); \
        num = __builtin_elementwise_fma(wKL, nKL, num); \
        num = __builtin_elementwise_fma(wKC, nKC, num); \
        num = __builtin_elementwise_fma(wKR, nKR, num); \
        f32x2 den = ((wAL + wAC) + (wAR + wBL)) + ((wBR + wKL) + (wKC + wKR)); \
        den = den + (f32x2)1.0f; \
        f32x2 rc = (f32x2){__builtin_amdgcn_rcpf(den.x), __builtin_amdgcn_rcpf(den.y)}; \
        psum = __builtin_elementwise_fma(num, rc, psum); }

    #pragma unroll
    for (int r = 0; r < 16; ++r) {
        // pair views of the rows
        f32x2 a01={a0,a1}, a12={a1,a2}, a23={a2,a3}, a34={a3,a4}, a45={a4,a5};
        f32x2 b01={b0,b1}, b12={b1,b2}, b23={b2,b3}, b34={b3,b4}, b45={b4,b5};
        f32x2 k01={k0,k1}, k12={k1,k2}, k23={k2,k3}, k34={k3,k4}, k45={k4,k5};

        // 10 packed exp2 on the VALU pipe, each arg consumed immediately
        f32x2 H01  = exp2p(earg2(b01, b12, WS1));   // H0,H1
        f32x2 H23  = exp2p(earg2(b23, b34, WS1));   // H2,H3
        f32x2 V12  = exp2p(earg2(b12, k12, WS1));   // V1,V2
        f32x2 V34  = exp2p(earg2(b34, k34, WS1));   // V3,V4
        f32x2 DL12 = exp2p(earg2(b12, k01, WS2));   // DL1,DL2
        f32x2 DL34 = exp2p(earg2(b34, k23, WS2));   // DL3,DL4
        f32x2 DR01 = exp2p(earg2(b01, k12, WS2));   // DR0,DR1
        f32x2 DR23 = exp2p(earg2(b23, k34, WS2));   // DR2,DR3
        f32x2 X1   = exp2p((f32x2){earg1(b4,b5,WS1), earg1(b5,k4,WS2)});  // H4, DL5
        f32x2 X2   = exp2p((f32x2){earg1(b4,k5,WS2), earg1(b4,k5,WS2)});  // DR4 (dup)

        // pixels (p0,p1): centers {b1,b2}
        PIXPAIR(b12, a01,a12,a23, b01,b23, k01,k12,k23,
                cDR01, cV12, cDL23,
                H01, ((f32x2){H01.y,H23.x}),
                DL12, V12, ((f32x2){DR01.y,DR23.x}))
        // pixels (p2,p3): centers {b3,b4}
        PIXPAIR(b34, a23,a34,a45, b23,b45, k23,k34,k45,
                cDR23, cV34, cDL45,
                H23, ((f32x2){H23.y,X1.x}),
                DL34, V34, ((f32x2){DR23.y,X2.x}))

        // rotate rows (full unroll -> renaming)
        a0=b0;a1=b1;a2=b2;a3=b3;a4=b4;a5=b5;
        b0=k0;b1=k1;b2=k2;b3=k3;b4=k4;b5=k5;
        k0=p0;k1=p1;k2=p2;k3=p3;k4=p4;k5=p5;
        // carried weights = this row's B-K edges
        cV12 = V12; cV34 = V34; cDR01 = DR01; cDR23 = DR23;
        cDL23 = (f32x2){DL12.y, DL34.x};
        cDL45 = (f32x2){DL34.y, X1.y};
        if (r < 14) { LOADROW(r+3, p0,p1,p2,p3,p4,p5) }
    }
#undef PIXPAIR
#undef LOADROW

    float ps = psum.x + psum.y;
    ps += __shfl_xor(ps, 1);
    ps += __shfl_xor(ps, 2);

    if ((t & 3) == 0) {
        out[(size_t)bid * 64 + (t >> 2)] = ps * (1.0f / 256.0f);
    }
}

extern "C" void kernel_launch(void* const* d_in, const int* in_sizes, int n_in,
                              void* d_out, int out_size, void* d_ws, size_t ws_size,
                              hipStream_t stream) {
    const float* x = (const float*)d_in[0];
    float* out     = (float*)d_out;
    // 1024 blocks x 256 threads (4 cols x 16 rows each)
    EdgePreserve_kernel<<<dim3(16 * 64), dim3(256), 0, stream>>>(x, out);
}

// Round 17
// 27.876 us; speedup vs baseline: 4.0729x; 1.7791x over previous
//
#include <hip/hip_runtime.h>

#define IMG_H 1024
#define IMG_W 1024

#define CC  (-0.1803368801111244f)     // -(1/8)*log2(e)
#define WS1 (-2.8853900817779270e-4f)  // log2(exp(-1/5000))
#define WS2 (-5.7707801635558540e-4f)  // log2(exp(-2/5000))

typedef __attribute__((ext_vector_type(2))) float f32x2;
typedef __attribute__((address_space(1))) const void gas_t;   // global
typedef __attribute__((address_space(3))) void las_t;         // LDS

__device__ __forceinline__ float e2(float y) { return __builtin_amdgcn_exp2f(y); }

__device__ __forceinline__ f32x2 earg2(f32x2 u, f32x2 v, float ws) {
    f32x2 d = u - v;
    return __builtin_elementwise_fma(d * d, (f32x2)CC, (f32x2)ws);
}
__device__ __forceinline__ float earg1(float u, float v, float ws) {
    float d = u - v;
    return fmaf(d * d, CC, ws);
}

#define VMCNT(n) asm volatile("s_waitcnt vmcnt(" #n ")" ::: "memory")
#define BAR()    { asm volatile("" ::: "memory"); __builtin_amdgcn_s_barrier(); asm volatile("" ::: "memory"); }

__global__ __launch_bounds__(256, 4) void EdgePreserve_kernel(const float* __restrict__ x,
                                                              float* __restrict__ out) {
    const int t    = threadIdx.x;
    const int lane = t & 63;
    const int wid  = t >> 6;
    const int bid  = blockIdx.x;        // b*64 + pool_row
    const int b    = bid >> 6;
    const int pr   = bid & 63;
    const int r0   = pr << 4;
    const int c0   = t << 2;            // 4 cols per thread

    __shared__ __align__(16) float lds[8][IMG_W];   // 8-row ring, 32 KB

    const float* base = x + (size_t)b * (IMG_H * IMG_W);

    // async DMA: this wave's 256-col quarter of image row r0+q -> ring slot (q+1)&7.
    // LDS dst is wave-uniform; HW adds lane*16. Zero VGPR cost -> deep prefetch.
#define DMA(q) { \
    int _r = r0 + (q); \
    int _rr = (_r < 0) ? -_r : ((_r >= IMG_H) ? (2*IMG_H-2-_r) : _r); \
    const float* _src = base + (size_t)_rr * IMG_W + (wid << 8) + (lane << 2); \
    __builtin_amdgcn_global_load_lds((gas_t*)_src, (las_t*)&lds[((q)+1) & 7][wid << 8], 16, 0, 0); }

    // read 6-col window {c0-1, c0..c0+3, c0+4} of staged row q via 3 conflict-free
    // ds_read_b128 (stride-16). Reflect: col -1 -> 1, col 1024 -> 1022.
    const int cL = (c0 == 0) ? 0 : c0 - 4;
    const int cR = (c0 == IMG_W - 4) ? IMG_W - 4 : c0 + 4;
#define READROW(q, d0,d1,d2,d3,d4,d5) { \
    const int _s = ((q)+1) & 7; \
    float4 _L = *reinterpret_cast<const float4*>(&lds[_s][cL]); \
    float4 _C = *reinterpret_cast<const float4*>(&lds[_s][c0]); \
    float4 _R = *reinterpret_cast<const float4*>(&lds[_s][cR]); \
    d0 = (c0 == 0) ? _L.y : _L.w; \
    d1 = _C.x; d2 = _C.y; d3 = _C.z; d4 = _C.w; \
    d5 = (c0 == IMG_W - 4) ? _R.z : _R.x; }

    // prologue: rows -1..3 in flight; rows -1,0,1 guaranteed after vmcnt(2)
    DMA(-1) DMA(0) DMA(1) DMA(2) DMA(3)
    VMCNT(2);
    BAR();

    // 3 register row buffers: a=r-1, b=r, k=r+1 (k loaded per iteration)
    float a0,a1,a2,a3,a4,a5, b0,b1,b2,b3,b4,b5, k0,k1,k2,k3,k4,k5;
    READROW(-1, a0,a1,a2,a3,a4,a5)
    READROW( 0, b0,b1,b2,b3,b4,b5)

    // carried A-B edge weights (R13 layout)
    f32x2 cV12  = (f32x2){e2(earg1(a1,b1,WS1)), e2(earg1(a2,b2,WS1))};
    f32x2 cV34  = (f32x2){e2(earg1(a3,b3,WS1)), e2(earg1(a4,b4,WS1))};
    f32x2 cDR01 = (f32x2){e2(earg1(a0,b1,WS2)), e2(earg1(a1,b2,WS2))};
    f32x2 cDR23 = (f32x2){e2(earg1(a2,b3,WS2)), e2(earg1(a3,b4,WS2))};
    f32x2 cDL23 = (f32x2){e2(earg1(a2,b1,WS2)), e2(earg1(a3,b2,WS2))};
    f32x2 cDL45 = (f32x2){e2(earg1(a4,b3,WS2)), e2(earg1(a5,b4,WS2))};

    f32x2 psum = (f32x2){0.0f, 0.0f};

#define PIXPAIR(ctr, nAL,nAC,nAR, nBL,nBR, nKL,nKC,nKR, wAL,wAC,wAR, wBL,wBR, wKL,wKC,wKR) { \
        f32x2 num = ctr; \
        num = __builtin_elementwise_fma(wAL, nAL, num); \
        num = __builtin_elementwise_fma(wAC, nAC, num); \
        num = __builtin_elementwise_fma(wAR, nAR, num); \
        num = __builtin_elementwise_fma(wBL, nBL, num); \
        num = __builtin_elementwise_fma(wBR, nBR, num); \
        num = __builtin_elementwise_fma(wKL, nKL, num); \
        num = __builtin_elementwise_fma(wKC, nKC, num); \
        num = __builtin_elementwise_fma(wKR, nKR, num); \
        f32x2 den = ((wAL + wAC) + (wAR + wBL)) + ((wBR + wKL) + (wKC + wKR)); \
        den = den + (f32x2)1.0f; \
        f32x2 rc = (f32x2){__builtin_amdgcn_rcpf(den.x), __builtin_amdgcn_rcpf(den.y)}; \
        psum = __builtin_elementwise_fma(num, rc, psum); }

    #pragma unroll
    for (int r = 0; r < 16; ++r) {
        // issue prefetch (row r+4) BEFORE the counted wait; never drain to 0.
        DMA(r + 4)
        VMCNT(3);            // this wave's row r+1 quarter has landed
        BAR();               // all waves' quarters have landed
        READROW(r + 1, k0,k1,k2,k3,k4,k5)

        // pair views
        f32x2 a01={a0,a1}, a12={a1,a2}, a23={a2,a3}, a34={a3,a4}, a45={a4,a5};
        f32x2 b01={b0,b1}, b12={b1,b2}, b23={b2,b3}, b34={b3,b4}, b45={b4,b5};
        f32x2 k01={k0,k1}, k12={k1,k2}, k23={k2,k3}, k34={k3,k4}, k45={k4,k5};

        // packed edge args, scalar trans exp2 (R13 core — best measured codegen)
        f32x2 aH01 = earg2(b01, b12, WS1);
        f32x2 aH23 = earg2(b23, b34, WS1);
        float aH4  = earg1(b4, b5, WS1);
        f32x2 aV12 = earg2(b12, k12, WS1);
        f32x2 aV34 = earg2(b34, k34, WS1);
        f32x2 aDL12 = earg2(b12, k01, WS2);
        f32x2 aDL34 = earg2(b34, k23, WS2);
        float aDL5  = earg1(b5, k4, WS2);
        f32x2 aDR01 = earg2(b01, k12, WS2);
        f32x2 aDR23 = earg2(b23, k34, WS2);
        float aDR4  = earg1(b4, k5, WS2);

        float H0 = e2(aH01.x), H1 = e2(aH01.y), H2 = e2(aH23.x), H3 = e2(aH23.y), H4 = e2(aH4);
        float V1 = e2(aV12.x), V2 = e2(aV12.y), V3 = e2(aV34.x), V4 = e2(aV34.y);
        float DL1 = e2(aDL12.x), DL2 = e2(aDL12.y), DL3 = e2(aDL34.x), DL4 = e2(aDL34.y), DL5 = e2(aDL5);
        float DR0 = e2(aDR01.x), DR1 = e2(aDR01.y), DR2 = e2(aDR23.x), DR3 = e2(aDR23.y), DR4 = e2(aDR4);

        f32x2 H01={H0,H1}, H12={H1,H2}, H23={H2,H3}, H34={H3,H4};
        f32x2 V12={V1,V2}, V34={V3,V4};
        f32x2 DL12={DL1,DL2}, DL34={DL3,DL4};
        f32x2 DR01={DR0,DR1}, DR23={DR2,DR3};

        // pixels (p0,p1): centers {b1,b2}
        PIXPAIR(b12, a01,a12,a23, b01,b23, k01,k12,k23,
                cDR01, cV12, cDL23,
                H01, H12, DL12, V12, ((f32x2){DR1,DR2}))
        // pixels (p2,p3): centers {b3,b4}
        PIXPAIR(b34, a23,a34,a45, b23,b45, k23,k34,k45,
                cDR23, cV34, cDL45,
                H23, H34, DL34, V34, ((f32x2){DR3,DR4}))

        // rotate (full unroll -> renaming) + carried update
        a0=b0;a1=b1;a2=b2;a3=b3;a4=b4;a5=b5;
        b0=k0;b1=k1;b2=k2;b3=k3;b4=k4;b5=k5;
        cV12 = V12; cV34 = V34; cDR01 = DR01; cDR23 = DR23;
        cDL23 = (f32x2){DL2, DL3};
        cDL45 = (f32x2){DL4, DL5};
    }
#undef PIXPAIR
#undef READROW
#undef DMA

    float ps = psum.x + psum.y;
    ps += __shfl_xor(ps, 1);
    ps += __shfl_xor(ps, 2);

    if ((t & 3) == 0) {
        out[(size_t)bid * 64 + (t >> 2)] = ps * (1.0f / 256.0f);
    }
}

extern "C" void kernel_launch(void* const* d_in, const int* in_sizes, int n_in,
                              void* d_out, int out_size, void* d_ws, size_t ws_size,
                              hipStream_t stream) {
    const float* x = (const float*)d_in[0];
    float* out     = (float*)d_out;
    // 1024 blocks x 256 threads (4 cols x 16 rows each); 4 blocks/CU (LDS 32KB, VGPR<=128)
    EdgePreserve_kernel<<<dim3(16 * 64), dim3(256), 0, stream>>>(x, out);
}

// Round 18
// 24.757 us; speedup vs baseline: 4.5861x; 1.1260x over previous
//
#include <hip/hip_runtime.h>

#define IMG_H 1024
#define IMG_W 1024

#define CC  (-0.1803368801111244f)     // -(1/8)*log2(e)
#define WS1 (-2.8853900817779270e-4f)  // log2(exp(-1/5000))
#define WS2 (-5.7707801635558540e-4f)  // log2(exp(-2/5000))

typedef __attribute__((ext_vector_type(2))) float f32x2;

__device__ __forceinline__ float e2(float y) { return __builtin_amdgcn_exp2f(y); }

__device__ __forceinline__ f32x2 earg2(f32x2 u, f32x2 v, float ws) {
    f32x2 d = u - v;
    return __builtin_elementwise_fma(d * d, (f32x2)CC, (f32x2)ws);
}
__device__ __forceinline__ float earg1(float u, float v, float ws) {
    float d = u - v;
    return fmaf(d * d, CC, ws);
}

// 14 edges between rows X (upper) and Y (lower):
// V_c=w(X_c,Y_c), DL_c=w(X_c,Y_{c-1}), DR_c=w(X_c,Y_{c+1})
#define ROWPAIR_EDGES(X0,X1,X2,X3,X4,X5, Y0,Y1,Y2,Y3,Y4,Y5, \
                      V1,V2,V3,V4, DL1,DL2,DL3,DL4,DL5, DR0,DR1,DR2,DR3,DR4) { \
    f32x2 aV12  = earg2((f32x2){X1,X2}, (f32x2){Y1,Y2}, WS1); \
    f32x2 aV34  = earg2((f32x2){X3,X4}, (f32x2){Y3,Y4}, WS1); \
    f32x2 aDL12 = earg2((f32x2){X1,X2}, (f32x2){Y0,Y1}, WS2); \
    f32x2 aDL34 = earg2((f32x2){X3,X4}, (f32x2){Y2,Y3}, WS2); \
    float aDL5  = earg1(X5, Y4, WS2); \
    f32x2 aDR01 = earg2((f32x2){X0,X1}, (f32x2){Y1,Y2}, WS2); \
    f32x2 aDR23 = earg2((f32x2){X2,X3}, (f32x2){Y3,Y4}, WS2); \
    float aDR4  = earg1(X4, Y5, WS2); \
    V1 = e2(aV12.x);  V2 = e2(aV12.y);  V3 = e2(aV34.x);  V4 = e2(aV34.y); \
    DL1 = e2(aDL12.x); DL2 = e2(aDL12.y); DL3 = e2(aDL34.x); DL4 = e2(aDL34.y); DL5 = e2(aDL5); \
    DR0 = e2(aDR01.x); DR1 = e2(aDR01.y); DR2 = e2(aDR23.x); DR3 = e2(aDR23.y); DR4 = e2(aDR4); }

// 5 horizontal edges within row X: H_c = w(X_c, X_{c+1})
#define ROW_H(X0,X1,X2,X3,X4,X5, H0,H1,H2,H3,H4) { \
    f32x2 aH01 = earg2((f32x2){X0,X1}, (f32x2){X1,X2}, WS1); \
    f32x2 aH23 = earg2((f32x2){X2,X3}, (f32x2){X3,X4}, WS1); \
    float aH4  = earg1(X4, X5, WS1); \
    H0 = e2(aH01.x); H1 = e2(aH01.y); H2 = e2(aH23.x); H3 = e2(aH23.y); H4 = e2(aH4); }

__global__ __launch_bounds__(256, 4) void EdgePreserve_kernel(const float* __restrict__ x,
                                                              float* __restrict__ out) {
    const int t   = threadIdx.x;
    const int bid = blockIdx.x;         // b*64 + pool_row
    const int b   = bid >> 6;
    const int pr  = bid & 63;
    const int r0  = pr << 4;
    const int c0  = t << 2;             // 4 cols per thread

    const float* base = x + (size_t)b * (IMG_H * IMG_W);
    const int cl = (c0 == 0) ? 1 : c0 - 1;
    const int cr = (c0 + 4 >= IMG_W) ? IMG_W - 2 : c0 + 4;

    // 6 row buffers: A=r-1, B=r, C=r+1, D=r+2; E,F = prefetch r+3, r+4
    float a0,a1,a2,a3,a4,a5, b0,b1,b2,b3,b4,b5, c1_0,c1_1,c1_2,c1_3,c1_4,c1_5,
          d0,d1,d2,d3,d4,d5, e0,e1,e2_,e3,e4,e5, f0,f1,f2,f3,f4,f5;

#define LOADROW(q, w0,w1,w2,w3,w4,w5) { \
    int _r = r0 + (q); \
    int _rr = (_r < 0) ? -_r : ((_r >= IMG_H) ? (2*IMG_H-2-_r) : _r); \
    const float* _rp = base + _rr * IMG_W; \
    float4 _v = *reinterpret_cast<const float4*>(_rp + c0); \
    w0 = _rp[cl]; w1 = _v.x; w2 = _v.y; w3 = _v.z; w4 = _v.w; w5 = _rp[cr]; }

    LOADROW(-1, a0,a1,a2,a3,a4,a5)
    LOADROW( 0, b0,b1,b2,b3,b4,b5)
    LOADROW( 1, c1_0,c1_1,c1_2,c1_3,c1_4,c1_5)
    LOADROW( 2, d0,d1,d2,d3,d4,d5)

    // carried A-B edges (rows r0-1, r0): 12 values
    f32x2 cV12, cV34, cDR01, cDR23;
    float pDL2, pDL3, pDL4, pDL5;
    {
        f32x2 aV  = earg2((f32x2){a1,a2}, (f32x2){b1,b2}, WS1);
        f32x2 aVb = earg2((f32x2){a3,a4}, (f32x2){b3,b4}, WS1);
        f32x2 aR  = earg2((f32x2){a0,a1}, (f32x2){b1,b2}, WS2);
        f32x2 aRb = earg2((f32x2){a2,a3}, (f32x2){b3,b4}, WS2);
        f32x2 aL  = earg2((f32x2){a2,a3}, (f32x2){b1,b2}, WS2);
        f32x2 aLb = earg2((f32x2){a4,a5}, (f32x2){b3,b4}, WS2);
        cV12  = (f32x2){e2(aV.x),  e2(aV.y)};
        cV34  = (f32x2){e2(aVb.x), e2(aVb.y)};
        cDR01 = (f32x2){e2(aR.x),  e2(aR.y)};
        cDR23 = (f32x2){e2(aRb.x), e2(aRb.y)};
        pDL2 = e2(aL.x);  pDL3 = e2(aL.y);
        pDL4 = e2(aLb.x); pDL5 = e2(aLb.y);
    }

    f32x2 psum = (f32x2){0.0f, 0.0f};

#define PIXPAIR(ctr, nAL,nAC,nAR, nBL,nBR, nKL,nKC,nKR, wAL,wAC,wAR, wBL,wBR, wKL,wKC,wKR) { \
        f32x2 num = ctr; \
        num = __builtin_elementwise_fma(wAL, nAL, num); \
        num = __builtin_elementwise_fma(wAC, nAC, num); \
        num = __builtin_elementwise_fma(wAR, nAR, num); \
        num = __builtin_elementwise_fma(wBL, nBL, num); \
        num = __builtin_elementwise_fma(wBR, nBR, num); \
        num = __builtin_elementwise_fma(wKL, nKL, num); \
        num = __builtin_elementwise_fma(wKC, nKC, num); \
        num = __builtin_elementwise_fma(wKR, nKR, num); \
        f32x2 den = ((wAL + wAC) + (wAR + wBL)) + ((wBR + wKL) + (wKC + wKR)); \
        den = den + (f32x2)1.0f; \
        f32x2 rc = (f32x2){__builtin_amdgcn_rcpf(den.x), __builtin_amdgcn_rcpf(den.y)}; \
        psum = __builtin_elementwise_fma(num, rc, psum); }

    // 8 fused iterations, 2 image rows each; fully unrolled
    #pragma unroll
    for (int i = 0; i < 8; ++i) {
        // prefetch rows 2i+3, 2i+4 (consumed next iteration as C,D)
        LOADROW(2*i + 3, e0,e1,e2_,e3,e4,e5)
        LOADROW(2*i + 4, f0,f1,f2,f3,f4,f5)

        // horizontal edges of B and C
        float HB0,HB1,HB2,HB3,HB4, HC0,HC1,HC2,HC3,HC4;
        ROW_H(b0,b1,b2,b3,b4,b5, HB0,HB1,HB2,HB3,HB4)
        ROW_H(c1_0,c1_1,c1_2,c1_3,c1_4,c1_5, HC0,HC1,HC2,HC3,HC4)

        // B-C and C-D edge sets (14 each)
        float BV1,BV2,BV3,BV4, BDL1,BDL2,BDL3,BDL4,BDL5, BDR0,BDR1,BDR2,BDR3,BDR4;
        float CV1,CV2,CV3,CV4, CDL1,CDL2,CDL3,CDL4,CDL5, CDR0,CDR1,CDR2,CDR3,CDR4;
        ROWPAIR_EDGES(b0,b1,b2,b3,b4,b5, c1_0,c1_1,c1_2,c1_3,c1_4,c1_5,
                      BV1,BV2,BV3,BV4, BDL1,BDL2,BDL3,BDL4,BDL5, BDR0,BDR1,BDR2,BDR3,BDR4)
        ROWPAIR_EDGES(c1_0,c1_1,c1_2,c1_3,c1_4,c1_5, d0,d1,d2,d3,d4,d5,
                      CV1,CV2,CV3,CV4, CDL1,CDL2,CDL3,CDL4,CDL5, CDR0,CDR1,CDR2,CDR3,CDR4)

        // pair views
        f32x2 a01={a0,a1}, a12={a1,a2}, a23={a2,a3}, a34={a3,a4}, a45={a4,a5};
        f32x2 b01={b0,b1}, b12={b1,b2}, b23={b2,b3}, b34={b3,b4}, b45={b4,b5};
        f32x2 c01={c1_0,c1_1}, c12={c1_1,c1_2}, c23={c1_2,c1_3}, c34={c1_3,c1_4}, c45={c1_4,c1_5};
        f32x2 d01={d0,d1}, d12={d1,d2}, d23={d2,d3}, d34={d3,d4}, d45={d4,d5};

        // ---- image row 2i (center B): up = carried A-B, down = B-C ----
        PIXPAIR(b12, a01,a12,a23, b01,b23, c01,c12,c23,
                cDR01, cV12, ((f32x2){pDL2,pDL3}),
                ((f32x2){HB0,HB1}), ((f32x2){HB1,HB2}),
                ((f32x2){BDL1,BDL2}), ((f32x2){BV1,BV2}), ((f32x2){BDR1,BDR2}))
        PIXPAIR(b34, a23,a34,a45, b23,b45, c23,c34,c45,
                cDR23, cV34, ((f32x2){pDL4,pDL5}),
                ((f32x2){HB2,HB3}), ((f32x2){HB3,HB4}),
                ((f32x2){BDL3,BDL4}), ((f32x2){BV3,BV4}), ((f32x2){BDR3,BDR4}))

        // ---- image row 2i+1 (center C): up = B-C, down = C-D ----
        PIXPAIR(c12, b01,b12,b23, c01,c23, d01,d12,d23,
                ((f32x2){BDR0,BDR1}), ((f32x2){BV1,BV2}), ((f32x2){BDL2,BDL3}),
                ((f32x2){HC0,HC1}), ((f32x2){HC1,HC2}),
                ((f32x2){CDL1,CDL2}), ((f32x2){CV1,CV2}), ((f32x2){CDR1,CDR2}))
        PIXPAIR(c34, b23,b34,b45, c23,c45, d23,d34,d45,
                ((f32x2){BDR2,BDR3}), ((f32x2){BV3,BV4}), ((f32x2){BDL4,BDL5}),
                ((f32x2){HC2,HC3}), ((f32x2){HC3,HC4}),
                ((f32x2){CDL3,CDL4}), ((f32x2){CV3,CV4}), ((f32x2){CDR3,CDR4}))

        // rotate rows by 2 (full unroll -> renaming)
        a0=c1_0;a1=c1_1;a2=c1_2;a3=c1_3;a4=c1_4;a5=c1_5;
        b0=d0;b1=d1;b2=d2;b3=d3;b4=d4;b5=d5;
        c1_0=e0;c1_1=e1;c1_2=e2_;c1_3=e3;c1_4=e4;c1_5=e5;
        d0=f0;d1=f1;d2=f2;d3=f3;d4=f4;d5=f5;
        // carried = this iter's C-D edges
        cV12 = (f32x2){CV1,CV2}; cV34 = (f32x2){CV3,CV4};
        cDR01 = (f32x2){CDR0,CDR1}; cDR23 = (f32x2){CDR2,CDR3};
        pDL2 = CDL2; pDL3 = CDL3; pDL4 = CDL4; pDL5 = CDL5;
    }
#undef PIXPAIR
#undef LOADROW

    float ps = psum.x + psum.y;
    ps += __shfl_xor(ps, 1);
    ps += __shfl_xor(ps, 2);

    if ((t & 3) == 0) {
        out[(size_t)bid * 64 + (t >> 2)] = ps * (1.0f / 256.0f);
    }
}

extern "C" void kernel_launch(void* const* d_in, const int* in_sizes, int n_in,
                              void* d_out, int out_size, void* d_ws, size_t ws_size,
                              hipStream_t stream) {
    const float* x = (const float*)d_in[0];
    float* out     = (float*)d_out;
    // 1024 blocks x 256 threads (4 cols x 16 rows each), 4 blocks/CU resident
    EdgePreserve_kernel<<<dim3(16 * 64), dim3(256), 0, stream>>>(x, out);
}